// Round 1
// baseline (10724.714 us; speedup 1.0000x reference)
//
#include <hip/hip_runtime.h>

// Problem: ConvMPN — N=2048 nodes, C=16, H=W=32, E=16384 edges.
// enc = concat([x, neigh, non_neigh]) (48 ch) -> conv3x3(48->32) -> conv3x3(32->32) -> conv3x3(32->16)
// neigh[v]  = sum over edges(a,+1,b): x[a] into b and x[b] into a
// nonneigh  = same with rel < 0.

#define N_NODES 2048
#define C_IN 16
#define HW 1024          // 32*32
#define PLANE 16384      // 16*32*32 floats per node image

// ---------------- scatter: edge-parallel atomic adds ----------------
__global__ __launch_bounds__(256) void scatter_edges(
    const float* __restrict__ x, const int* __restrict__ edges,
    float* __restrict__ neigh, float* __restrict__ nonneigh, int E)
{
    int e    = blockIdx.x >> 1;
    int side = blockIdx.x & 1;
    if (e >= E) return;
    int a   = edges[3 * e + 0];
    int rel = edges[3 * e + 1];
    int b   = edges[3 * e + 2];
    float* dstbase = (rel > 0) ? neigh : nonneigh;
    int dn = side ? a : b;   // destination node
    int sn = side ? b : a;   // source node
    const float4* src = (const float4*)(x + (size_t)sn * PLANE);
    float* dst = dstbase + (size_t)dn * PLANE;
    // 16384 floats = 4096 float4 per edge-side; 256 threads -> 16 iters
    for (int i = threadIdx.x; i < PLANE / 4; i += 256) {
        float4 v = src[i];
        atomicAdd(dst + 4 * i + 0, v.x);
        atomicAdd(dst + 4 * i + 1, v.y);
        atomicAdd(dst + 4 * i + 2, v.z);
        atomicAdd(dst + 4 * i + 3, v.w);
    }
}

// ---------------- conv3x3, pad=1, stride=1 ----------------
// Block: 256 threads = 8 rows x 32 cols of one image n; grid = N * 4 row-groups.
// LDS tile: CI x 10 x 34 (halo). Each thread: 1 pixel, register tile of 16 co.
// Weights indexed uniformly (loop counters only) -> compiler scalarizes to s_load.
template <int CI, int CO>
__global__ __launch_bounds__(256) void conv3x3_k(
    const float* __restrict__ in0, const float* __restrict__ in1,
    const float* __restrict__ in2, const float* __restrict__ wt,
    const float* __restrict__ bias, float* __restrict__ out)
{
    __shared__ float tile[CI * 10 * 34];
    int n  = blockIdx.x >> 2;
    int r0 = (blockIdx.x & 3) * 8;

    // cooperative halo load
    for (int idx = threadIdx.x; idx < CI * 10 * 34; idx += 256) {
        int ci  = idx / 340;
        int rem = idx - ci * 340;
        int rr  = rem / 34;
        int cc  = rem - rr * 34;
        int gr = r0 + rr - 1;
        int gc = cc - 1;
        float v = 0.0f;
        if (gr >= 0 && gr < 32 && gc >= 0 && gc < 32) {
            if (CI == 48) {
                // concat of three 16-channel tensors
                const float* src = (ci < 16) ? in0 : (ci < 32 ? in1 : in2);
                int c = ci & 15;
                v = src[((size_t)n * 16 + c) * HW + gr * 32 + gc];
            } else {
                v = in0[((size_t)n * CI + ci) * HW + gr * 32 + gc];
            }
        }
        tile[idx] = v;
    }
    __syncthreads();

    int r = threadIdx.x >> 5;   // 0..7
    int c = threadIdx.x & 31;   // 0..31

    for (int cb = 0; cb < CO; cb += 16) {
        float acc[16];
#pragma unroll
        for (int j = 0; j < 16; j++) acc[j] = bias[cb + j];

        for (int ci = 0; ci < CI; ci++) {
            float v[9];
#pragma unroll
            for (int kh = 0; kh < 3; kh++)
#pragma unroll
                for (int kw = 0; kw < 3; kw++)
                    v[kh * 3 + kw] = tile[(ci * 10 + r + kh) * 34 + (c + kw)];
#pragma unroll
            for (int j = 0; j < 16; j++) {
                const float* wp = wt + ((size_t)(cb + j) * CI + ci) * 9;
#pragma unroll
                for (int k = 0; k < 9; k++) acc[j] += v[k] * wp[k];
            }
        }
#pragma unroll
        for (int j = 0; j < 16; j++)
            out[(((size_t)n * CO + cb + j) * 32 + (r0 + r)) * 32 + c] = acc[j];
    }
}

extern "C" void kernel_launch(void* const* d_in, const int* in_sizes, int n_in,
                              void* d_out, int out_size, void* d_ws, size_t ws_size,
                              hipStream_t stream)
{
    const float* x     = (const float*)d_in[0];
    const int*   edges = (const int*)d_in[1];
    const float* w1    = (const float*)d_in[2];
    const float* b1    = (const float*)d_in[3];
    const float* w2    = (const float*)d_in[4];
    const float* b2    = (const float*)d_in[5];
    const float* w3    = (const float*)d_in[6];
    const float* b3    = (const float*)d_in[7];
    float* out = (float*)d_out;

    const int E = in_sizes[1] / 3;              // 16384
    const int n_nodes = in_sizes[0] / PLANE;    // 2048

    // workspace layout (floats):
    //   [0 .. 32Mi)   neigh      (N*16*1024)          -- later reused as h2 (first half)
    //   [32Mi..64Mi)  nonneigh                         -- later reused as h2 (second half)
    //   [64Mi..128Mi) h1         (N*32*1024)
    float* ws       = (float*)d_ws;
    float* neigh    = ws;
    float* nonneigh = ws + (size_t)n_nodes * PLANE;
    float* h1       = ws + (size_t)2 * n_nodes * PLANE;
    float* h2       = ws;   // reuse neigh+nonneigh region after conv1

    // zero the neigh / non_neigh accumulators (ws is poisoned with 0xAA)
    hipMemsetAsync(neigh, 0, (size_t)2 * n_nodes * PLANE * sizeof(float), stream);

    // scatter-add over edges (2 sides per edge)
    scatter_edges<<<2 * E, 256, 0, stream>>>(x, edges, neigh, nonneigh, E);

    // conv1: 48 -> 32
    conv3x3_k<48, 32><<<n_nodes * 4, 256, 0, stream>>>(x, neigh, nonneigh, w1, b1, h1);
    // conv2: 32 -> 32
    conv3x3_k<32, 32><<<n_nodes * 4, 256, 0, stream>>>(h1, nullptr, nullptr, w2, b2, h2);
    // conv3: 32 -> 16
    conv3x3_k<32, 16><<<n_nodes * 4, 256, 0, stream>>>(h2, nullptr, nullptr, w3, b3, out);
}

// Round 2
// 4112.044 us; speedup vs baseline: 2.6081x; 2.6081x over previous
//
#include <hip/hip_runtime.h>

// ConvMPN — N=2048 nodes, C=16, H=W=32, E=16384 edges.
// enc = concat([x, neigh, non_neigh]) (48ch) -> conv3x3(48->32) -> conv3x3(32->32) -> conv3x3(32->16)
// R2: scatter+atomicAdd (6.8ms, 4x write amplification) replaced by CSR build + gather (no atomics).

#define N_NODES 2048
#define HW 1024          // 32*32
#define PLANE 16384      // 16*32*32 floats per node image
#define CAP 128          // max degree per (node, sign); mean is 8, Poisson tail ~0 at 128

__device__ inline void f4add(float4& a, const float4 b) {
    a.x += b.x; a.y += b.y; a.z += b.z; a.w += b.w;
}

// ---------------- build per-(node,sign) adjacency lists ----------------
__global__ __launch_bounds__(256) void build_lists(
    const int* __restrict__ edges, int E, int* __restrict__ cnt, int* __restrict__ lists)
{
    int e = blockIdx.x * 256 + threadIdx.x;
    if (e >= E) return;
    int a   = edges[3 * e + 0];
    int rel = edges[3 * e + 1];
    int b   = edges[3 * e + 2];
    int s = (rel > 0) ? 0 : 1;
    int slot = atomicAdd(&cnt[b * 2 + s], 1);
    if (slot < CAP) lists[((size_t)(b * 2 + s)) * CAP + slot] = a;
    slot = atomicAdd(&cnt[a * 2 + s], 1);
    if (slot < CAP) lists[((size_t)(a * 2 + s)) * CAP + slot] = b;
}

// ---------------- gather: one block per node, no atomics ----------------
__global__ __launch_bounds__(256) void gather_nodes(
    const float* __restrict__ x, const int* __restrict__ cnt, const int* __restrict__ lists,
    float* __restrict__ neigh, float* __restrict__ nonneigh)
{
    int v = blockIdx.x;
    __shared__ int slist[2 * CAP];
    __shared__ int sdeg[2];
    if (threadIdx.x < 2) sdeg[threadIdx.x] = min(cnt[v * 2 + threadIdx.x], CAP);
    for (int i = threadIdx.x; i < 2 * CAP; i += 256)
        slist[i] = lists[(size_t)v * 2 * CAP + i];
    __syncthreads();

    int t = threadIdx.x;
    for (int s = 0; s < 2; s++) {
        float4 acc[16];
#pragma unroll
        for (int i = 0; i < 16; i++) acc[i] = make_float4(0.f, 0.f, 0.f, 0.f);
        int d = sdeg[s];
        for (int k = 0; k < d; k++) {
            const float4* sp = (const float4*)(x + (size_t)slist[s * CAP + k] * PLANE);
#pragma unroll
            for (int i = 0; i < 16; i++) f4add(acc[i], sp[i * 256 + t]);
        }
        float4* dst = (float4*)((s ? nonneigh : neigh) + (size_t)v * PLANE);
#pragma unroll
        for (int i = 0; i < 16; i++) dst[i * 256 + t] = acc[i];
    }
}

// ---------------- conv3x3, pad=1, stride=1 ----------------
// Block: 256 threads = 8 rows x 32 cols of one image n; grid = N * 4 row-groups.
// LDS tile: CI x 10 x 34 (halo). Each thread: 1 pixel, register tile of 16 co.
template <int CI, int CO>
__global__ __launch_bounds__(256) void conv3x3_k(
    const float* __restrict__ in0, const float* __restrict__ in1,
    const float* __restrict__ in2, const float* __restrict__ wt,
    const float* __restrict__ bias, float* __restrict__ out)
{
    __shared__ float tile[CI * 10 * 34];
    int n  = blockIdx.x >> 2;
    int r0 = (blockIdx.x & 3) * 8;

    for (int idx = threadIdx.x; idx < CI * 10 * 34; idx += 256) {
        int ci  = idx / 340;
        int rem = idx - ci * 340;
        int rr  = rem / 34;
        int cc  = rem - rr * 34;
        int gr = r0 + rr - 1;
        int gc = cc - 1;
        float v = 0.0f;
        if (gr >= 0 && gr < 32 && gc >= 0 && gc < 32) {
            if (CI == 48) {
                const float* src = (ci < 16) ? in0 : (ci < 32 ? in1 : in2);
                int c = ci & 15;
                v = src[((size_t)n * 16 + c) * HW + gr * 32 + gc];
            } else {
                v = in0[((size_t)n * CI + ci) * HW + gr * 32 + gc];
            }
        }
        tile[idx] = v;
    }
    __syncthreads();

    int r = threadIdx.x >> 5;   // 0..7
    int c = threadIdx.x & 31;   // 0..31

    for (int cb = 0; cb < CO; cb += 16) {
        float acc[16];
#pragma unroll
        for (int j = 0; j < 16; j++) acc[j] = bias[cb + j];

        for (int ci = 0; ci < CI; ci++) {
            float v[9];
#pragma unroll
            for (int kh = 0; kh < 3; kh++)
#pragma unroll
                for (int kw = 0; kw < 3; kw++)
                    v[kh * 3 + kw] = tile[(ci * 10 + r + kh) * 34 + (c + kw)];
#pragma unroll
            for (int j = 0; j < 16; j++) {
                const float* wp = wt + ((size_t)(cb + j) * CI + ci) * 9;
#pragma unroll
                for (int k = 0; k < 9; k++) acc[j] += v[k] * wp[k];
            }
        }
#pragma unroll
        for (int j = 0; j < 16; j++)
            out[(((size_t)n * CO + cb + j) * 32 + (r0 + r)) * 32 + c] = acc[j];
    }
}

extern "C" void kernel_launch(void* const* d_in, const int* in_sizes, int n_in,
                              void* d_out, int out_size, void* d_ws, size_t ws_size,
                              hipStream_t stream)
{
    const float* x     = (const float*)d_in[0];
    const int*   edges = (const int*)d_in[1];
    const float* w1    = (const float*)d_in[2];
    const float* b1    = (const float*)d_in[3];
    const float* w2    = (const float*)d_in[4];
    const float* b2    = (const float*)d_in[5];
    const float* w3    = (const float*)d_in[6];
    const float* b3    = (const float*)d_in[7];
    float* out = (float*)d_out;

    const int E = in_sizes[1] / 3;              // 16384
    const int n_nodes = in_sizes[0] / PLANE;    // 2048

    // workspace layout (floats), 512 MiB total:
    //   [0 .. 32Mi)    neigh    (128 MiB)   -- reused as h2 (first half) after conv1
    //   [32Mi .. 64Mi) nonneigh (128 MiB)   -- reused as h2 (second half)
    //   [64Mi..128Mi)  h1       (256 MiB)   -- counters+lists aliased at its start
    //                                          (consumed by gather BEFORE conv1 writes h1)
    float* ws       = (float*)d_ws;
    float* neigh    = ws;
    float* nonneigh = ws + (size_t)n_nodes * PLANE;
    float* h1       = ws + (size_t)2 * n_nodes * PLANE;
    float* h2       = ws;
    int*   cnt      = (int*)h1;                       // N*2 ints = 16 KB
    int*   lists    = cnt + (size_t)n_nodes * 2;      // N*2*CAP ints = 2 MiB

    // zero only the degree counters (ws is poisoned with 0xAA)
    hipMemsetAsync(cnt, 0, (size_t)n_nodes * 2 * sizeof(int), stream);

    build_lists<<<(E + 255) / 256, 256, 0, stream>>>(edges, E, cnt, lists);
    gather_nodes<<<n_nodes, 256, 0, stream>>>(x, cnt, lists, neigh, nonneigh);

    // conv1: 48 -> 32
    conv3x3_k<48, 32><<<n_nodes * 4, 256, 0, stream>>>(x, neigh, nonneigh, w1, b1, h1);
    // conv2: 32 -> 32
    conv3x3_k<32, 32><<<n_nodes * 4, 256, 0, stream>>>(h1, nullptr, nullptr, w2, b2, h2);
    // conv3: 32 -> 16
    conv3x3_k<32, 16><<<n_nodes * 4, 256, 0, stream>>>(h2, nullptr, nullptr, w3, b3, out);
}

// Round 3
// 1318.292 us; speedup vs baseline: 8.1353x; 3.1192x over previous
//
#include <hip/hip_runtime.h>

// ConvMPN — N=2048, C=16, H=W=32, E=16384.
// R3: convs moved to bf16 MFMA (16x16x32). Pipeline:
//   build_lists -> xpose(x->bf16 pixel-major) -> gather_enc (bf16 [px][64])
//   -> conv1 mfma (K=48 in 2 chunks of 32, zero-padded) -> h1 bf16 [px][32]
//   -> conv2 -> h2 -> conv3 -> out fp32 NCHW.
// LDS tile stride padded (72/40 ch) => 2-way bank aliasing only (free, m136).

#define NNODES 2048
#define HW 1024
#define PLANE 16384
#define CAP 128

typedef float v4f __attribute__((ext_vector_type(4)));
typedef short v8s __attribute__((ext_vector_type(8)));

__device__ inline unsigned short f2bfu(float f) {
    unsigned u = __float_as_uint(f);
    u += 0x7fffu + ((u >> 16) & 1u);   // round-to-nearest-even
    return (unsigned short)(u >> 16);
}
__device__ inline unsigned pk2(float a, float b) {
    return (unsigned)f2bfu(a) | ((unsigned)f2bfu(b) << 16);
}
__device__ inline void add2(float& a, float& b, unsigned u) {
    a += __uint_as_float(u << 16);
    b += __uint_as_float(u & 0xffff0000u);
}

// ---------------- adjacency lists ----------------
__global__ __launch_bounds__(256) void build_lists(
    const int* __restrict__ edges, int E, int* __restrict__ cnt, int* __restrict__ lists)
{
    int e = blockIdx.x * 256 + threadIdx.x;
    if (e >= E) return;
    int a = edges[3 * e + 0];
    int rel = edges[3 * e + 1];
    int b = edges[3 * e + 2];
    int s = (rel > 0) ? 0 : 1;
    int slot = atomicAdd(&cnt[b * 2 + s], 1);
    if (slot < CAP) lists[((size_t)(b * 2 + s)) * CAP + slot] = a;
    slot = atomicAdd(&cnt[a * 2 + s], 1);
    if (slot < CAP) lists[((size_t)(a * 2 + s)) * CAP + slot] = b;
}

// ---------------- x fp32 NCHW -> bf16 [n][1024 px][16 ch] ----------------
__global__ __launch_bounds__(256) void xpose_bf16(
    const float* __restrict__ x, ushort* __restrict__ xb)
{
    int n = blockIdx.x, t = threadIdx.x;
    const float4* src = (const float4*)(x + (size_t)n * PLANE);
    float vv[64];
#pragma unroll
    for (int i = 0; i < 16; i++) {
        float4 v = src[i * 256 + t];          // ci=i, pixels 4t..4t+3 (coalesced)
        vv[i * 4 + 0] = v.x; vv[i * 4 + 1] = v.y; vv[i * 4 + 2] = v.z; vv[i * 4 + 3] = v.w;
    }
    uint4* dst = (uint4*)(xb + (size_t)n * HW * 16);
#pragma unroll
    for (int j = 0; j < 4; j++) {
        uint4 o0, o1;
        o0.x = pk2(vv[0 * 4 + j], vv[1 * 4 + j]);
        o0.y = pk2(vv[2 * 4 + j], vv[3 * 4 + j]);
        o0.z = pk2(vv[4 * 4 + j], vv[5 * 4 + j]);
        o0.w = pk2(vv[6 * 4 + j], vv[7 * 4 + j]);
        o1.x = pk2(vv[8 * 4 + j], vv[9 * 4 + j]);
        o1.y = pk2(vv[10 * 4 + j], vv[11 * 4 + j]);
        o1.z = pk2(vv[12 * 4 + j], vv[13 * 4 + j]);
        o1.w = pk2(vv[14 * 4 + j], vv[15 * 4 + j]);
        dst[(4 * t + j) * 2 + 0] = o0;
        dst[(4 * t + j) * 2 + 1] = o1;
    }
}

// ---------------- gather -> enc bf16 [n][1024 px][64 ch] ----------------
// ch 0..15 = x, 16..31 = neigh, 32..47 = nonneigh, 48..63 = zeros (K-pad for mfma)
__global__ __launch_bounds__(256) void gather_enc(
    const ushort* __restrict__ xb, const int* __restrict__ cnt,
    const int* __restrict__ lists, ushort* __restrict__ enc)
{
    int v = blockIdx.x, t = threadIdx.x;
    __shared__ int slist[2 * CAP];
    __shared__ int sdeg[2];
    if (t < 2) sdeg[t] = min(cnt[v * 2 + t], CAP);
    slist[t] = lists[(size_t)v * 2 * CAP + t];   // 256 == 2*CAP
    __syncthreads();

    uint4* edst = (uint4*)(enc + (size_t)v * HW * 64);
    const uint4* xsrc = (const uint4*)(xb + (size_t)v * HW * 16);
    const uint4 z = make_uint4(0, 0, 0, 0);
#pragma unroll
    for (int j = 0; j < 4; j++) {
        int q = 4 * t + j;
        edst[q * 8 + 0] = xsrc[q * 2 + 0];
        edst[q * 8 + 1] = xsrc[q * 2 + 1];
        edst[q * 8 + 6] = z;
        edst[q * 8 + 7] = z;
    }
    for (int s = 0; s < 2; s++) {
        float acc[64];
#pragma unroll
        for (int i = 0; i < 64; i++) acc[i] = 0.f;
        int d = sdeg[s];
        for (int k = 0; k < d; k++) {
            const uint4* sp = (const uint4*)(xb + (size_t)slist[s * CAP + k] * HW * 16);
#pragma unroll
            for (int j = 0; j < 4; j++) {
                uint4 p0 = sp[(4 * t + j) * 2 + 0];
                uint4 p1 = sp[(4 * t + j) * 2 + 1];
                add2(acc[j * 16 + 0],  acc[j * 16 + 1],  p0.x);
                add2(acc[j * 16 + 2],  acc[j * 16 + 3],  p0.y);
                add2(acc[j * 16 + 4],  acc[j * 16 + 5],  p0.z);
                add2(acc[j * 16 + 6],  acc[j * 16 + 7],  p0.w);
                add2(acc[j * 16 + 8],  acc[j * 16 + 9],  p1.x);
                add2(acc[j * 16 + 10], acc[j * 16 + 11], p1.y);
                add2(acc[j * 16 + 12], acc[j * 16 + 13], p1.z);
                add2(acc[j * 16 + 14], acc[j * 16 + 15], p1.w);
            }
        }
#pragma unroll
        for (int j = 0; j < 4; j++) {
            uint4 o0, o1;
            o0.x = pk2(acc[j * 16 + 0],  acc[j * 16 + 1]);
            o0.y = pk2(acc[j * 16 + 2],  acc[j * 16 + 3]);
            o0.z = pk2(acc[j * 16 + 4],  acc[j * 16 + 5]);
            o0.w = pk2(acc[j * 16 + 6],  acc[j * 16 + 7]);
            o1.x = pk2(acc[j * 16 + 8],  acc[j * 16 + 9]);
            o1.y = pk2(acc[j * 16 + 10], acc[j * 16 + 11]);
            o1.z = pk2(acc[j * 16 + 12], acc[j * 16 + 13]);
            o1.w = pk2(acc[j * 16 + 14], acc[j * 16 + 15]);
            edst[(4 * t + j) * 8 + 2 + s * 2 + 0] = o0;
            edst[(4 * t + j) * 8 + 2 + s * 2 + 1] = o1;
        }
    }
}

// ---------------- conv3x3 via bf16 MFMA 16x16x32 ----------------
// in: bf16 [n][1024][CIP_G]; out: bf16 [n][1024][CO] or fp32 NCHW.
// Block = quarter image (8 rows). LDS tile: 10 rows x 32 px x CIP_L (stride-padded).
// Wave holds B-fragments (weights) in registers; A from LDS per (mtile,khw).
// MFMA layouts (m89/m118 verified): A m=lane&15,k=quad*8+j; B n=lane&15,k=quad*8+j;
//                                   D col(n)=lane&15, row(m)=quad*4+reg.
template<int CI_REAL, int CIP_G, int CIP_L, int KCH, int CO, bool OUT_F32>
__global__ __launch_bounds__(256) void conv_mfma(
    const ushort* __restrict__ in, const float* __restrict__ wt,
    const float* __restrict__ bias, ushort* __restrict__ outb,
    float* __restrict__ outf)
{
    __shared__ ushort tile[320 * CIP_L];
    const int n = blockIdx.x >> 2;
    const int r0 = (blockIdx.x & 3) * 8;
    const int CH4 = CIP_G / 8;                   // uint4 chunks per pixel

    const uint4* gsrc = (const uint4*)(in + (size_t)n * HW * CIP_G);
    for (int idx = threadIdx.x; idx < 320 * CH4; idx += 256) {
        int lp = idx / CH4;                      // local pixel 0..319 (10 rows x 32)
        int ch = idx - lp * CH4;
        int gr = r0 - 1 + (lp >> 5);
        uint4 val = make_uint4(0, 0, 0, 0);
        if (gr >= 0 && gr < 32) val = gsrc[(size_t)(gr * 32 + (lp & 31)) * CH4 + ch];
        *(uint4*)&tile[lp * CIP_L + ch * 8] = val;
    }
    __syncthreads();

    const int wv = threadIdx.x >> 6;
    const int lane = threadIdx.x & 63;
    const int l15 = lane & 15;
    const int kq = lane >> 4;                    // quad 0..3

    const int cotile = (CO == 32) ? (wv >> 1) : 0;
    const int cob = cotile * 16;
    const int nco = cob + l15;

    // B fragments: one per (khw, kchunk), in registers
    v8s bfrag[9 * KCH];
#pragma unroll
    for (int khw = 0; khw < 9; khw++)
#pragma unroll
        for (int kc = 0; kc < KCH; kc++) {
            v8s b;
#pragma unroll
            for (int j = 0; j < 8; j++) {
                int k = kc * 32 + kq * 8 + j;
                float w = (k < CI_REAL) ? wt[((size_t)nco * CI_REAL + k) * 9 + khw] : 0.f;
                b[j] = (short)f2bfu(w);
            }
            bfrag[khw * KCH + kc] = b;
        }
    const float bv = bias[nco];

    int mt0, mtstep, nmt;
    if (CO == 32) { mt0 = wv & 1; mtstep = 2; nmt = 8; }
    else          { mt0 = wv;     mtstep = 4; nmt = 4; }

    for (int it = 0; it < nmt; it++) {
        int mtile = mt0 + it * mtstep;           // 16 px = half-row tiles
        int r = r0 + (mtile >> 1);
        int c = (mtile & 1) * 16 + l15;          // this lane's A-row pixel column
        v4f acc = {bv, bv, bv, bv};
#pragma unroll
        for (int khw = 0; khw < 9; khw++) {
            int dh = khw / 3 - 1, dw = (khw % 3) - 1;
            int rr = r + dh;
            if (rr < 0 || rr > 31) continue;     // wave-uniform (zero-pad row)
            int cc = c + dw;
            bool okc = (cc >= 0) && (cc <= 31);
            int lp = (rr - r0 + 1) * 32 + (okc ? cc : 0);
#pragma unroll
            for (int kc = 0; kc < KCH; kc++) {
                v8s a = *(const v8s*)&tile[lp * CIP_L + kc * 32 + kq * 8];
                if (!okc) a = (v8s)0;            // zero-pad column (per-lane)
                acc = __builtin_amdgcn_mfma_f32_16x16x32_bf16(a, bfrag[khw * KCH + kc], acc, 0, 0, 0);
            }
        }
        int pbase = r * 32 + (mtile & 1) * 16 + kq * 4;   // first pixel of this lane's 4 rows
        if (OUT_F32) {
            float4 o; o.x = acc[0]; o.y = acc[1]; o.z = acc[2]; o.w = acc[3];
            *(float4*)(outf + ((size_t)n * CO + nco) * HW + pbase) = o;
        } else {
#pragma unroll
            for (int reg = 0; reg < 4; reg++)
                outb[((size_t)n * HW + pbase + reg) * CO + nco] = (ushort)f2bfu(acc[reg]);
        }
    }
}

extern "C" void kernel_launch(void* const* d_in, const int* in_sizes, int n_in,
                              void* d_out, int out_size, void* d_ws, size_t ws_size,
                              hipStream_t stream)
{
    const float* x     = (const float*)d_in[0];
    const int*   edges = (const int*)d_in[1];
    const float* w1    = (const float*)d_in[2];
    const float* b1    = (const float*)d_in[3];
    const float* w2    = (const float*)d_in[4];
    const float* b2    = (const float*)d_in[5];
    const float* w3    = (const float*)d_in[6];
    const float* b3    = (const float*)d_in[7];
    float* out = (float*)d_out;

    const int E = in_sizes[1] / 3;   // 16384

    // ws layout (ushort units), ~450 MiB total:
    //   enc: [n][1024][64] bf16 (256 MiB)  -- reused as h2 after conv1
    //   h1:  [n][1024][32] bf16 (128 MiB)
    //   xb:  [n][1024][16] bf16 (64 MiB)
    //   cnt/lists: ints (~2 MiB)
    ushort* enc = (ushort*)d_ws;
    ushort* h1  = enc + (size_t)NNODES * HW * 64;
    ushort* xb  = h1  + (size_t)NNODES * HW * 32;
    int*    cnt   = (int*)(xb + (size_t)NNODES * HW * 16);
    int*    lists = cnt + NNODES * 2;
    ushort* h2  = enc;

    hipMemsetAsync(cnt, 0, NNODES * 2 * sizeof(int), stream);
    build_lists<<<(E + 255) / 256, 256, 0, stream>>>(edges, E, cnt, lists);
    xpose_bf16<<<NNODES, 256, 0, stream>>>(x, xb);
    gather_enc<<<NNODES, 256, 0, stream>>>(xb, cnt, lists, enc);

    // conv1: 48 -> 32  (K chunks: 0..31 real, 32..63 = 16 real + 16 zero-pad)
    conv_mfma<48, 64, 72, 2, 32, false><<<NNODES * 4, 256, 0, stream>>>(enc, w1, b1, h1, nullptr);
    // conv2: 32 -> 32
    conv_mfma<32, 32, 40, 1, 32, false><<<NNODES * 4, 256, 0, stream>>>(h1, w2, b2, h2, nullptr);
    // conv3: 32 -> 16, fp32 NCHW output
    conv_mfma<32, 32, 40, 1, 16, true><<<NNODES * 4, 256, 0, stream>>>(h2, w3, b3, nullptr, out);
}